// Round 7
// baseline (9770.866 us; speedup 1.0000x reference)
//
#include <hip/hip_runtime.h>

#define NHID 256
#define BSHIFT 6                 // 64 rows per bucket
#define BROWS  (1 << BSHIFT)
#define MAXNB  1568              // LDS histogram capacity (>= ceil(100000/64)=1563)

typedef __attribute__((ext_vector_type(8))) short short8;
typedef __attribute__((ext_vector_type(4))) float floatx4;
typedef __attribute__((ext_vector_type(4))) float float4v;
typedef __attribute__((ext_vector_type(4))) int int4v;

static __device__ __forceinline__ short f2bf(float f) {
    unsigned u = __float_as_uint(f);
    unsigned r = (u + 0x7fffu + ((u >> 16) & 1u)) >> 16;
    return (short)r;
}
static __device__ __forceinline__ unsigned pk2(float a, float b) {
    return ((unsigned)(unsigned short)f2bf(a)) | (((unsigned)(unsigned short)f2bf(b)) << 16);
}

// ------- W transpose+cast (both weights) + zero-init of bucket counters ------------
__global__ void transpose_cast2(const float* __restrict__ W1, short* __restrict__ W1t,
                                const float* __restrict__ W2, short* __restrict__ W2t,
                                int K1, int K2, int* __restrict__ bcnt, int nb)
{
    int idx = blockIdx.x * 256 + threadIdx.x;
    if (idx < nb) bcnt[idx] = 0;                 // folded memset
    int n1 = K1 * NHID;
    if (idx < n1) {
        int k = idx >> 8;
        int n = idx & 255;
        W1t[(size_t)n * K1 + k] = f2bf(W1[idx]);
    } else {
        int j = idx - n1;
        if (j < K2 * NHID) {
            int k = j >> 8;
            int n = j & 255;
            W2t[(size_t)n * K2 + k] = f2bf(W2[j]);
        }
    }
}

// ---------------- MFMA GEMM: C[M x 256](bf16) = A[M x K] @ Bt[n][k](bf16) ----------
template<bool ABF16>
__global__ __launch_bounds__(512) void gemm_mfma(
    const void* __restrict__ Ap, const short* __restrict__ Bt,
    short* __restrict__ C, int M, int K)
{
    __shared__ __align__(16) short As[128][40];
    __shared__ __align__(16) short Bs[256][40];

    int tid  = threadIdx.x;
    int m0   = blockIdx.x * 128;
    int lane = tid & 63;
    int wid  = tid >> 6;      // 0..7
    int wm   = wid >> 2;      // 0..1 : 64-row block
    int wn   = wid & 3;       // 0..3 : 64-col block
    int quad = lane >> 4;
    int l16  = lane & 15;

    floatx4 acc[4][4] = {};

    for (int k0 = 0; k0 < K; k0 += 32) {
        if (ABF16) {
            const short* A = (const short*)Ap;
            int tr = tid >> 2, tc = (tid & 3) * 8;      // 128 rows x 32 cols
            int gm = m0 + tr;
            int4v v = {0, 0, 0, 0};
            if (gm < M) v = __builtin_nontemporal_load((const int4v*)(A + (size_t)gm * K + k0 + tc));
            *(int4v*)&As[tr][tc] = v;
        } else {
            const float* A = (const float*)Ap;
            int tr = tid >> 3, tc = (tid & 7) * 4;      // 64 rows per pass
            #pragma unroll
            for (int p = 0; p < 2; ++p) {
                int m = p * 64 + tr, gm = m0 + m;
                float4v v = {0.f, 0.f, 0.f, 0.f};
                if (gm < M) v = __builtin_nontemporal_load((const float4v*)(A + (size_t)gm * K + k0 + tc));
                short4 s;
                s.x = f2bf(v.x); s.y = f2bf(v.y); s.z = f2bf(v.z); s.w = f2bf(v.w);
                *(short4*)&As[m][tc] = s;
            }
        }
        {
            int nr = tid >> 2, nc = (tid & 3) * 8;      // 128 rows per pass
            #pragma unroll
            for (int p = 0; p < 2; ++p) {
                int n = p * 128 + nr;
                *(int4*)&Bs[n][nc] = *(const int4*)(Bt + (size_t)n * K + k0 + nc);
            }
        }
        __syncthreads();

        short8 af[4], bfr[4];
        #pragma unroll
        for (int t = 0; t < 4; ++t) {
            af[t]  = *(const short8*)&As[wm * 64 + t * 16 + l16][quad * 8];
            bfr[t] = *(const short8*)&Bs[wn * 64 + t * 16 + l16][quad * 8];
        }
        #pragma unroll
        for (int tm = 0; tm < 4; ++tm)
            #pragma unroll
            for (int tn = 0; tn < 4; ++tn)
                acc[tm][tn] = __builtin_amdgcn_mfma_f32_16x16x32_bf16(
                    af[tm], bfr[tn], acc[tm][tn], 0, 0, 0);
        __syncthreads();
    }

    #pragma unroll
    for (int tm = 0; tm < 4; ++tm) {
        #pragma unroll
        for (int r = 0; r < 4; ++r) {
            int row = m0 + wm * 64 + tm * 16 + quad * 4 + r;
            if (row < M) {
                #pragma unroll
                for (int tn = 0; tn < 4; ++tn) {
                    int col = wn * 64 + tn * 16 + l16;
                    C[(size_t)row * NHID + col] = f2bf(acc[tm][tn][r]);
                }
            }
        }
    }
}

// ================= CSR-lite build: bucket-grouped edge list (3 passes) =============

__global__ __launch_bounds__(256) void hist_lds(
    const int* __restrict__ erow, int* __restrict__ bcnt, int E, int nb)
{
    __shared__ int h[MAXNB];
    for (int i = threadIdx.x; i < nb; i += 256) h[i] = 0;
    __syncthreads();
    int stride = gridDim.x * 256;
    for (int i = blockIdx.x * 256 + threadIdx.x; i < E; i += stride)
        atomicAdd(&h[erow[i] >> BSHIFT], 1);
    __syncthreads();
    for (int i = threadIdx.x; i < nb; i += 256) {
        int v = h[i];
        if (v) atomicAdd(&bcnt[i], v);
    }
}

__global__ __launch_bounds__(1024) void scan_buckets(
    const int* __restrict__ bcnt, int* __restrict__ bstart,
    int* __restrict__ bcur, int nb, int E)
{
    __shared__ int ws[16];
    __shared__ int carry_s;
    int tid = threadIdx.x, lane = tid & 63, w = tid >> 6;
    if (tid == 0) carry_s = 0;
    __syncthreads();
    for (int base = 0; base < nb; base += 1024) {
        int i = base + tid;
        int v = (i < nb) ? bcnt[i] : 0;
        int x = v;
        #pragma unroll
        for (int off = 1; off < 64; off <<= 1) {
            int y = __shfl_up(x, off, 64);
            if (lane >= off) x += y;
        }
        if (lane == 63) ws[w] = x;
        __syncthreads();
        if (w == 0 && lane < 16) {
            int s2 = ws[lane];
            #pragma unroll
            for (int off = 1; off < 16; off <<= 1) {
                int y = __shfl_up(s2, off, 16);
                if (lane >= off) s2 += y;
            }
            ws[lane] = s2;
        }
        __syncthreads();
        int add = (w > 0) ? ws[w - 1] : 0;
        int incl = x + add;
        int c = carry_s;
        int excl = incl - v + c;
        if (i < nb) { bstart[i] = excl; bcur[i] = excl; }
        __syncthreads();
        if (tid == 1023) carry_s = c + incl;
        __syncthreads();
    }
    if (tid == 0) bstart[nb] = E;
}

// stage with LDS ranking: one global atomic per (WG,bucket). Row low bits
// packed into bits 20..25 of the col word (col < 2^17).
__global__ __launch_bounds__(256) void stage_lds(
    const int* __restrict__ erow, const int* __restrict__ ecol,
    const float* __restrict__ eval,
    int* __restrict__ bcur, int2* __restrict__ staged, int E, int nb, int chunk)
{
    __shared__ int h[MAXNB];
    int s = blockIdx.x * chunk;
    int e = min(E, s + chunk);
    for (int i = threadIdx.x; i < nb; i += 256) h[i] = 0;
    __syncthreads();
    for (int i = s + threadIdx.x; i < e; i += 256)
        atomicAdd(&h[erow[i] >> BSHIFT], 1);
    __syncthreads();
    for (int i = threadIdx.x; i < nb; i += 256) {
        int v = h[i];
        h[i] = v ? atomicAdd(&bcur[i], v) : 0;   // reserve span; h[i] = my base
    }
    __syncthreads();
    for (int i = s + threadIdx.x; i < e; i += 256) {
        int r = erow[i];
        int b = r >> BSHIFT;
        int pos = atomicAdd(&h[b], 1);           // LDS rank within reservation
        staged[pos] = make_int2(ecol[i] | ((r & (BROWS - 1)) << 20), __float_as_int(eval[i]));
    }
}

// ===== Fused bucket-SpMM: 1 WG per 64-row bucket, LDS fp32 accumulator,
// wave-per-edge full-row gather (preserves the 8-line fetch correlation),
// ds_add_f32 conflict-free (word idx === lane mod 32), fused bias+PReLU.
static __device__ __forceinline__ void edge_acc(
    const int2 ev, const short* __restrict__ dense,
    float (*accs)[NHID], int lane)
{
    int rl = ((unsigned)ev.x) >> 20;
    int c  = ev.x & 0xFFFFF;
    float v = __int_as_float(ev.y);
    const short* dr = dense + (size_t)c * NHID;
    #pragma unroll
    for (int j = 0; j < 4; ++j) {
        unsigned short u = *(const unsigned short*)(dr + j * 64 + lane);
        float f = __uint_as_float(((unsigned)u) << 16);
        atomicAdd(&accs[rl][j * 64 + lane], v * f);
    }
}

template<bool OUT_BF16>
__global__ __launch_bounds__(1024, 8) void spmm_bucket(
    const int* __restrict__ bstart, const int2* __restrict__ staged,
    const short* __restrict__ dense,
    const float* __restrict__ bias, const float* __restrict__ alpha_p,
    void* __restrict__ outp, int N)
{
    __shared__ float accs[BROWS][NHID];          // 64 KB
    int b   = blockIdx.x;
    int r0  = b << BSHIFT;
    int nr  = min(N - r0, BROWS);
    int tid = threadIdx.x;
    int lane = tid & 63;
    int wv   = tid >> 6;                         // 0..15

    {   // zero LDS
        float4v z = {0.f, 0.f, 0.f, 0.f};
        float* p = &accs[0][0];
        #pragma unroll
        for (int i = 0; i < 4; ++i)
            *(float4v*)(p + (tid + i * 1024) * 4) = z;
    }
    __syncthreads();

    int s = bstart[b], e = bstart[b + 1];
    int i = s + wv * 2;
    for (; i + 1 < e; i += 32) {                 // 2 edges per wave per iter
        int2 e0 = staged[i];
        int2 e1 = staged[i + 1];
        edge_acc(e0, dense, accs, lane);
        edge_acc(e1, dense, accs, lane);
    }
    if (i < e) edge_acc(staged[i], dense, accs, lane);
    __syncthreads();

    float alpha = alpha_p[0];
    if (OUT_BF16) {
        short* op = (short*)outp;
        for (int idx = tid; idx < nr * 128; idx += 1024) {
            int r = idx >> 7, c2 = (idx & 127) * 2;
            float a0 = accs[r][c2]     + bias[c2];
            float a1 = accs[r][c2 + 1] + bias[c2 + 1];
            a0 = (a0 >= 0.f) ? a0 : alpha * a0;
            a1 = (a1 >= 0.f) ? a1 : alpha * a1;
            *(unsigned*)(op + (size_t)(r0 + r) * NHID + c2) = pk2(a0, a1);
        }
    } else {
        float* op = (float*)outp;
        for (int idx = tid; idx < nr * 64; idx += 1024) {
            int r = idx >> 6, c4 = (idx & 63) * 4;
            float4v o;
            o.x = accs[r][c4]     + bias[c4];
            o.y = accs[r][c4 + 1] + bias[c4 + 1];
            o.z = accs[r][c4 + 2] + bias[c4 + 2];
            o.w = accs[r][c4 + 3] + bias[c4 + 3];
            o.x = (o.x >= 0.f) ? o.x : alpha * o.x;
            o.y = (o.y >= 0.f) ? o.y : alpha * o.y;
            o.z = (o.z >= 0.f) ? o.z : alpha * o.z;
            o.w = (o.w >= 0.f) ? o.w : alpha * o.w;
            __builtin_nontemporal_store(o, (float4v*)(op + (size_t)(r0 + r) * NHID + c4));
        }
    }
}

extern "C" void kernel_launch(void* const* d_in, const int* in_sizes, int n_in,
                              void* d_out, int out_size, void* d_ws, size_t ws_size,
                              hipStream_t stream)
{
    const float* x     = (const float*)d_in[0];
    const int*   erow  = (const int*)d_in[1];
    const int*   ecol  = (const int*)d_in[2];
    const float* eval  = (const float*)d_in[3];
    const float* W1    = (const float*)d_in[4];
    const float* b1    = (const float*)d_in[5];
    const float* W2    = (const float*)d_in[6];
    const float* b2    = (const float*)d_in[7];
    const float* alpha = (const float*)d_in[8];

    int NFEAT = 512;
    int N = in_sizes[0] / NFEAT;   // 100000
    int E = in_sizes[1];           // 3200000
    float* out = (float*)d_out;

    // Workspace layout (same footprint as previous rounds, ~128.8 MB)
    char* wsp = (char*)d_ws;
    short* support_b = (short*)wsp;  wsp += (size_t)N * NHID * sizeof(short);  // 51.2 MB
    short* h1b       = (short*)wsp;  wsp += (size_t)N * NHID * sizeof(short);  // 51.2 MB
    int2*  staged    = (int2*)wsp;   wsp += (size_t)E * sizeof(int2);          // 25.6 MB
    int*   csr       = (int*)wsp;    wsp += ((size_t)(N + 1) * sizeof(int) + 15) & ~(size_t)15;
    short* W1t       = (short*)wsp;  wsp += (size_t)NFEAT * NHID * sizeof(short);
    short* W2t       = (short*)wsp;  wsp += (size_t)NHID * NHID * sizeof(short);

    int NB = (N + BROWS - 1) >> BSHIFT;         // 1563 buckets of 64 rows

    // small CSR scratch lives in the dedicated csr slot (400 KB >> 19 KB needed)
    int* bcnt   = csr;                          // NB
    int* bstart = bcnt + NB;                    // NB + 1  (read by spmm_bucket)
    int* bcur   = bstart + NB + 1;              // NB

    // ---- Weight transpose+cast + bcnt zero (one launch) ----
    transpose_cast2<<<((NFEAT + NHID) * NHID + 255) / 256, 256, 0, stream>>>(
        W1, W1t, W2, W2t, NFEAT, NHID, bcnt, NB);

    // ---- bucket-grouped edge list (3 passes, LDS-aggregated atomics) ----
    int nwg = 256;
    int chunk = (E + nwg - 1) / nwg;            // 12500 edges per WG
    hist_lds<<<nwg, 256, 0, stream>>>(erow, bcnt, E, NB);
    scan_buckets<<<1, 1024, 0, stream>>>(bcnt, bstart, bcur, NB, E);
    stage_lds<<<nwg, 256, 0, stream>>>(erow, ecol, eval, bcur, staged, E, NB, chunk);

    int ggrid = (N + 127) / 128;

    // ---- Layer 1 ----
    gemm_mfma<false><<<ggrid, 512, 0, stream>>>(x, W1t, support_b, N, NFEAT);
    spmm_bucket<true><<<NB, 1024, 0, stream>>>(bstart, staged, support_b, b1, alpha, h1b, N);
    // ---- Layer 2 ----
    gemm_mfma<true><<<ggrid, 512, 0, stream>>>(h1b, W2t, support_b, N, NHID);
    spmm_bucket<false><<<NB, 1024, 0, stream>>>(bstart, staged, support_b, b2, alpha, out, N);
}

// Round 8
// 936.737 us; speedup vs baseline: 10.4307x; 10.4307x over previous
//
#include <hip/hip_runtime.h>

#define NHID 256
#define BSHIFT 6                 // 64 rows per bucket
#define BROWS  (1 << BSHIFT)
#define MAXNB  1568              // LDS histogram capacity (>= ceil(100000/64)=1563)

typedef __attribute__((ext_vector_type(8))) short short8;
typedef __attribute__((ext_vector_type(4))) float floatx4;
typedef __attribute__((ext_vector_type(4))) float float4v;
typedef __attribute__((ext_vector_type(4))) int int4v;

static __device__ __forceinline__ short f2bf(float f) {
    unsigned u = __float_as_uint(f);
    unsigned r = (u + 0x7fffu + ((u >> 16) & 1u)) >> 16;
    return (short)r;
}
static __device__ __forceinline__ unsigned pk2(float a, float b) {
    return ((unsigned)(unsigned short)f2bf(a)) | (((unsigned)(unsigned short)f2bf(b)) << 16);
}

// ------- W transpose+cast (both weights) + zero-init of bucket counters ------------
__global__ void transpose_cast2(const float* __restrict__ W1, short* __restrict__ W1t,
                                const float* __restrict__ W2, short* __restrict__ W2t,
                                int K1, int K2, int* __restrict__ bcnt, int nb)
{
    int idx = blockIdx.x * 256 + threadIdx.x;
    if (idx < nb) bcnt[idx] = 0;                 // folded memset
    int n1 = K1 * NHID;
    if (idx < n1) {
        int k = idx >> 8;
        int n = idx & 255;
        W1t[(size_t)n * K1 + k] = f2bf(W1[idx]);
    } else {
        int j = idx - n1;
        if (j < K2 * NHID) {
            int k = j >> 8;
            int n = j & 255;
            W2t[(size_t)n * K2 + k] = f2bf(W2[j]);
        }
    }
}

// ---------------- MFMA GEMM: C[M x 256](bf16) = A[M x K] @ Bt[n][k](bf16) ----------
template<bool ABF16>
__global__ __launch_bounds__(512) void gemm_mfma(
    const void* __restrict__ Ap, const short* __restrict__ Bt,
    short* __restrict__ C, int M, int K)
{
    __shared__ __align__(16) short As[128][40];
    __shared__ __align__(16) short Bs[256][40];

    int tid  = threadIdx.x;
    int m0   = blockIdx.x * 128;
    int lane = tid & 63;
    int wid  = tid >> 6;      // 0..7
    int wm   = wid >> 2;      // 0..1 : 64-row block
    int wn   = wid & 3;       // 0..3 : 64-col block
    int quad = lane >> 4;
    int l16  = lane & 15;

    floatx4 acc[4][4] = {};

    for (int k0 = 0; k0 < K; k0 += 32) {
        if (ABF16) {
            const short* A = (const short*)Ap;
            int tr = tid >> 2, tc = (tid & 3) * 8;      // 128 rows x 32 cols
            int gm = m0 + tr;
            int4v v = {0, 0, 0, 0};
            if (gm < M) v = __builtin_nontemporal_load((const int4v*)(A + (size_t)gm * K + k0 + tc));
            *(int4v*)&As[tr][tc] = v;
        } else {
            const float* A = (const float*)Ap;
            int tr = tid >> 3, tc = (tid & 7) * 4;      // 64 rows per pass
            #pragma unroll
            for (int p = 0; p < 2; ++p) {
                int m = p * 64 + tr, gm = m0 + m;
                float4v v = {0.f, 0.f, 0.f, 0.f};
                if (gm < M) v = __builtin_nontemporal_load((const float4v*)(A + (size_t)gm * K + k0 + tc));
                short4 s;
                s.x = f2bf(v.x); s.y = f2bf(v.y); s.z = f2bf(v.z); s.w = f2bf(v.w);
                *(short4*)&As[m][tc] = s;
            }
        }
        {
            int nr = tid >> 2, nc = (tid & 3) * 8;      // 128 rows per pass
            #pragma unroll
            for (int p = 0; p < 2; ++p) {
                int n = p * 128 + nr;
                *(int4*)&Bs[n][nc] = *(const int4*)(Bt + (size_t)n * K + k0 + nc);
            }
        }
        __syncthreads();

        short8 af[4], bfr[4];
        #pragma unroll
        for (int t = 0; t < 4; ++t) {
            af[t]  = *(const short8*)&As[wm * 64 + t * 16 + l16][quad * 8];
            bfr[t] = *(const short8*)&Bs[wn * 64 + t * 16 + l16][quad * 8];
        }
        #pragma unroll
        for (int tm = 0; tm < 4; ++tm)
            #pragma unroll
            for (int tn = 0; tn < 4; ++tn)
                acc[tm][tn] = __builtin_amdgcn_mfma_f32_16x16x32_bf16(
                    af[tm], bfr[tn], acc[tm][tn], 0, 0, 0);
        __syncthreads();
    }

    #pragma unroll
    for (int tm = 0; tm < 4; ++tm) {
        #pragma unroll
        for (int r = 0; r < 4; ++r) {
            int row = m0 + wm * 64 + tm * 16 + quad * 4 + r;
            if (row < M) {
                #pragma unroll
                for (int tn = 0; tn < 4; ++tn) {
                    int col = wn * 64 + tn * 16 + l16;
                    C[(size_t)row * NHID + col] = f2bf(acc[tm][tn][r]);
                }
            }
        }
    }
}

// ================= CSR build: LDS-aggregated binning, wave-boosted =================

// 256 WGs x 1024 threads: 16 waves/WG = 4 waves/SIMD for latency hiding; the
// per-WG LDS aggregation keeps the global-atomic flush at ~400K total.
__global__ __launch_bounds__(1024) void hist_lds(
    const int* __restrict__ erow, int* __restrict__ bcnt, int E, int nb)
{
    __shared__ int h[MAXNB];
    for (int i = threadIdx.x; i < nb; i += 1024) h[i] = 0;
    __syncthreads();
    int stride = gridDim.x * 1024;
    for (int i = blockIdx.x * 1024 + threadIdx.x; i < E; i += stride)
        atomicAdd(&h[erow[i] >> BSHIFT], 1);
    __syncthreads();
    for (int i = threadIdx.x; i < nb; i += 1024) {
        int v = h[i];
        if (v) atomicAdd(&bcnt[i], v);
    }
}

__global__ __launch_bounds__(1024) void scan_buckets(
    const int* __restrict__ bcnt, int* __restrict__ bstart,
    int* __restrict__ bcur, int nb, int E)
{
    __shared__ int ws[16];
    __shared__ int carry_s;
    int tid = threadIdx.x, lane = tid & 63, w = tid >> 6;
    if (tid == 0) carry_s = 0;
    __syncthreads();
    for (int base = 0; base < nb; base += 1024) {
        int i = base + tid;
        int v = (i < nb) ? bcnt[i] : 0;
        int x = v;
        #pragma unroll
        for (int off = 1; off < 64; off <<= 1) {
            int y = __shfl_up(x, off, 64);
            if (lane >= off) x += y;
        }
        if (lane == 63) ws[w] = x;
        __syncthreads();
        if (w == 0 && lane < 16) {
            int s2 = ws[lane];
            #pragma unroll
            for (int off = 1; off < 16; off <<= 1) {
                int y = __shfl_up(s2, off, 16);
                if (lane >= off) s2 += y;
            }
            ws[lane] = s2;
        }
        __syncthreads();
        int add = (w > 0) ? ws[w - 1] : 0;
        int incl = x + add;
        int c = carry_s;
        int excl = incl - v + c;
        if (i < nb) { bstart[i] = excl; bcur[i] = excl; }
        __syncthreads();
        if (tid == 1023) carry_s = c + incl;
        __syncthreads();
    }
    if (tid == 0) bstart[nb] = E;
}

// stage with LDS ranking: one global atomic per (WG,bucket). Row low bits
// packed into bits 20..25 of the col word (col < 2^17). 1024 threads.
__global__ __launch_bounds__(1024) void stage_lds(
    const int* __restrict__ erow, const int* __restrict__ ecol,
    const float* __restrict__ eval,
    int* __restrict__ bcur, int2* __restrict__ staged, int E, int nb, int chunk)
{
    __shared__ int h[MAXNB];
    int s = blockIdx.x * chunk;
    int e = min(E, s + chunk);
    for (int i = threadIdx.x; i < nb; i += 1024) h[i] = 0;
    __syncthreads();
    for (int i = s + threadIdx.x; i < e; i += 1024)
        atomicAdd(&h[erow[i] >> BSHIFT], 1);
    __syncthreads();
    for (int i = threadIdx.x; i < nb; i += 1024) {
        int v = h[i];
        h[i] = v ? atomicAdd(&bcur[i], v) : 0;   // reserve span; h[i] = my base
    }
    __syncthreads();
    for (int i = s + threadIdx.x; i < e; i += 1024) {
        int r = erow[i];
        int b = r >> BSHIFT;
        int pos = atomicAdd(&h[b], 1);           // LDS rank within reservation
        staged[pos] = make_int2(ecol[i] | ((r & (BROWS - 1)) << 20), __float_as_int(eval[i]));
    }
}

// one WG per bucket: derive per-row offsets (LDS counters), emit row_ptr,
// and place edges at exact CSR slots (contiguous ~16 KB window per WG).
__global__ __launch_bounds__(512) void place_rowptr(
    const int* __restrict__ bstart, const int2* __restrict__ staged,
    int2* __restrict__ ep, int* __restrict__ row_ptr, int N, int E)
{
    __shared__ int rcnt[BROWS];
    __shared__ int rbase[BROWS];
    int b  = blockIdx.x;
    int r0 = b << BSHIFT;
    int nr = min(N - r0, BROWS);
    int s = bstart[b], e = bstart[b + 1];
    if (threadIdx.x < BROWS) rcnt[threadIdx.x] = 0;
    __syncthreads();
    for (int i = s + threadIdx.x; i < e; i += 512) {
        int rl = ((unsigned)staged[i].x) >> 20;
        atomicAdd(&rcnt[rl], 1);
    }
    __syncthreads();
    if (threadIdx.x < BROWS) {          // wave 0: exclusive scan of 64 counts
        int v = rcnt[threadIdx.x];
        int x = v;
        #pragma unroll
        for (int off = 1; off < 64; off <<= 1) {
            int y = __shfl_up(x, off, 64);
            if (threadIdx.x >= off) x += y;
        }
        int excl = s + x - v;
        rbase[threadIdx.x] = excl;
        if (threadIdx.x < nr) row_ptr[r0 + threadIdx.x] = excl;
        rcnt[threadIdx.x] = 0;          // reuse as fill counters
    }
    __syncthreads();
    for (int i = s + threadIdx.x; i < e; i += 512) {
        int2 sv = staged[i];
        int rl = ((unsigned)sv.x) >> 20;
        int slot = rbase[rl] + atomicAdd(&rcnt[rl], 1);
        ep[slot] = make_int2(sv.x & 0xFFFFF, sv.y);
    }
    if (b == gridDim.x - 1 && threadIdx.x == 0) row_ptr[N] = E;
}

// ---------------- SpMM: split-wave, 16B gathers, packed edges, bias+PReLU ----------
static __device__ __forceinline__ void fma8(float* acc, uint4 g, float v)
{
    acc[0] += v * __uint_as_float(g.x << 16);
    acc[1] += v * __uint_as_float(g.x & 0xffff0000u);
    acc[2] += v * __uint_as_float(g.y << 16);
    acc[3] += v * __uint_as_float(g.y & 0xffff0000u);
    acc[4] += v * __uint_as_float(g.z << 16);
    acc[5] += v * __uint_as_float(g.z & 0xffff0000u);
    acc[6] += v * __uint_as_float(g.w << 16);
    acc[7] += v * __uint_as_float(g.w & 0xffff0000u);
}

template<bool OUT_BF16>
__global__ __launch_bounds__(256) void spmm_split(
    const int* __restrict__ row_ptr, const int2* __restrict__ ep,
    const short* __restrict__ dense,
    const float* __restrict__ bias, const float* __restrict__ alpha_p,
    void* __restrict__ outp, int nrows)
{
    int wid  = (blockIdx.x * blockDim.x + threadIdx.x) >> 6;
    int lane = threadIdx.x & 63;
    if (wid >= nrows) return;
    int half = lane >> 5;
    int l32  = lane & 31;
    int s = row_ptr[wid], e = row_ptr[wid + 1];
    int fo = l32 * 8;                       // bf16 elem offset; 16 B per lane

    float acc[8] = {};
    int i = s;
    for (; i + 3 < e; i += 4) {             // 4 edges per iter, 2 per half
        int2 e0 = ep[i + half];
        int2 e1 = ep[i + 2 + half];
        uint4 g0 = *(const uint4*)(dense + (size_t)e0.x * NHID + fo);
        uint4 g1 = *(const uint4*)(dense + (size_t)e1.x * NHID + fo);
        fma8(acc, g0, __int_as_float(e0.y));
        fma8(acc, g1, __int_as_float(e1.y));
    }
    for (; i < e; i += 2) {                 // remainder (0..3 edges)
        int j = i + half;
        if (j < e) {
            int2 e0 = ep[j];
            uint4 g0 = *(const uint4*)(dense + (size_t)e0.x * NHID + fo);
            fma8(acc, g0, __int_as_float(e0.y));
        }
    }

    #pragma unroll
    for (int k = 0; k < 8; ++k) acc[k] += __shfl_xor(acc[k], 32, 64);

    float alpha = alpha_p[0];
    float4 b0 = *(const float4*)(bias + fo);
    float4 b1 = *(const float4*)(bias + fo + 4);
    float r[8];
    r[0] = acc[0] + b0.x; r[1] = acc[1] + b0.y; r[2] = acc[2] + b0.z; r[3] = acc[3] + b0.w;
    r[4] = acc[4] + b1.x; r[5] = acc[5] + b1.y; r[6] = acc[6] + b1.z; r[7] = acc[7] + b1.w;
    #pragma unroll
    for (int k = 0; k < 8; ++k) r[k] = (r[k] >= 0.f) ? r[k] : alpha * r[k];

    if (OUT_BF16) {
        // feeds gemm2: store through cache (L3-resident for the next reader)
        if (half == 0) {
            uint4 o;
            o.x = pk2(r[0], r[1]); o.y = pk2(r[2], r[3]);
            o.z = pk2(r[4], r[5]); o.w = pk2(r[6], r[7]);
            *(uint4*)((short*)outp + (size_t)wid * NHID + fo) = o;
        }
    } else {
        // final output: nothing reads it, keep it out of the caches
        float4v ov;
        if (half) { ov.x = r[4]; ov.y = r[5]; ov.z = r[6]; ov.w = r[7]; }
        else      { ov.x = r[0]; ov.y = r[1]; ov.z = r[2]; ov.w = r[3]; }
        __builtin_nontemporal_store(ov, (float4v*)((float*)outp + (size_t)wid * NHID + fo + half * 4));
    }
}

extern "C" void kernel_launch(void* const* d_in, const int* in_sizes, int n_in,
                              void* d_out, int out_size, void* d_ws, size_t ws_size,
                              hipStream_t stream)
{
    const float* x     = (const float*)d_in[0];
    const int*   erow  = (const int*)d_in[1];
    const int*   ecol  = (const int*)d_in[2];
    const float* eval  = (const float*)d_in[3];
    const float* W1    = (const float*)d_in[4];
    const float* b1    = (const float*)d_in[5];
    const float* W2    = (const float*)d_in[6];
    const float* b2    = (const float*)d_in[7];
    const float* alpha = (const float*)d_in[8];

    int NFEAT = 512;
    int N = in_sizes[0] / NFEAT;   // 100000
    int E = in_sizes[1];           // 3200000
    float* out = (float*)d_out;

    // Workspace layout (~128.8 MB)
    char* wsp = (char*)d_ws;
    short* support_b = (short*)wsp;  wsp += (size_t)N * NHID * sizeof(short);  // 51.2 MB
    short* h1b       = (short*)wsp;  wsp += (size_t)N * NHID * sizeof(short);  // 51.2 MB
    int2*  ep        = (int2*)wsp;   wsp += (size_t)E * sizeof(int2);          // 25.6 MB
    int*   row_ptr   = (int*)wsp;    wsp += ((size_t)(N + 1) * sizeof(int) + 15) & ~(size_t)15;
    short* W1t       = (short*)wsp;  wsp += (size_t)NFEAT * NHID * sizeof(short);
    short* W2t       = (short*)wsp;  wsp += (size_t)NHID * NHID * sizeof(short);

    int NB = (N + BROWS - 1) >> BSHIFT;         // buckets of 64 rows (1563)

    // scratch aliased into h1b (dead until spmm1 writes it)
    int* bcnt   = (int*)h1b;                    // NB
    int* bstart = bcnt + NB;                    // NB + 1
    int* bcur   = bstart + NB + 1;              // NB

    // stage buffer aliased into support_b (dead until gemm1 writes it)
    int2* staged = (int2*)support_b;            // E * 8B = 25.6 MB <= 51.2 MB

    // ---- Weight transpose+cast + bcnt zero (one launch) ----
    transpose_cast2<<<((NFEAT + NHID) * NHID + 255) / 256, 256, 0, stream>>>(
        W1, W1t, W2, W2t, NFEAT, NHID, bcnt, NB);

    // ---- CSR build (LDS-aggregated binning, wave-boosted) ----
    int nwg = 256;
    int chunk = (E + nwg - 1) / nwg;            // 12500 edges per WG
    hist_lds<<<nwg, 1024, 0, stream>>>(erow, bcnt, E, NB);
    scan_buckets<<<1, 1024, 0, stream>>>(bcnt, bstart, bcur, NB, E);
    stage_lds<<<nwg, 1024, 0, stream>>>(erow, ecol, eval, bcur, staged, E, NB, chunk);
    place_rowptr<<<NB, 512, 0, stream>>>(bstart, staged, ep, row_ptr, N, E);

    int ggrid = (N + 127) / 128;
    int spmm_blocks = (N + 3) / 4;

    // ---- Layer 1 ----
    gemm_mfma<false><<<ggrid, 512, 0, stream>>>(x, W1t, support_b, N, NFEAT);
    spmm_split<true><<<spmm_blocks, 256, 0, stream>>>(row_ptr, ep, support_b, b1, alpha, h1b, N);
    // ---- Layer 2 ----
    gemm_mfma<true><<<ggrid, 512, 0, stream>>>(h1b, W2t, support_b, N, NHID);
    spmm_split<false><<<spmm_blocks, 256, 0, stream>>>(row_ptr, ep, support_b, b2, alpha, out, N);
}